// Round 1
// baseline (3180.372 us; speedup 1.0000x reference)
//
#include <hip/hip_runtime.h>
#include <stdint.h>

#define Mdim 8192
#define Kdim 4096
#define Ndim 11008
#define KBLK 32            // Kdim / 128
#define NBLK 86            // Ndim / 128
#define FP8MAX 448.0f
#define QEPS 1e-12f

typedef float v4f __attribute__((ext_vector_type(4)));

__device__ __forceinline__ void async16(void* lds, const void* g) {
  __builtin_amdgcn_global_load_lds(
      (const __attribute__((address_space(1))) unsigned int*)g,
      (__attribute__((address_space(3))) unsigned int*)lds, 16, 0, 0);
}

// ---------------- activation quantize: (1 x 128) blocks along K ----------------
// 32 lanes per block, 4 elems/lane via float4. Scales stored transposed [KBLK][M].
__global__ __launch_bounds__(256) void quant_x_kernel(const float* __restrict__ x,
                                                      uint8_t* __restrict__ qx,
                                                      float* __restrict__ sx) {
  const int tid = blockIdx.x * 256 + threadIdx.x;
  const int64_t base = (int64_t)tid * 4;
  const float4 v = *(const float4*)(x + base);
  float a = fmaxf(fmaxf(fabsf(v.x), fabsf(v.y)), fmaxf(fabsf(v.z), fabsf(v.w)));
#pragma unroll
  for (int off = 16; off >= 1; off >>= 1) a = fmaxf(a, __shfl_xor(a, off, 32));
  const float scale = fmaxf(a, QEPS) / FP8MAX;  // same rounding chain as reference
  int p = __builtin_amdgcn_cvt_pk_fp8_f32(v.x / scale, v.y / scale, 0, false);
  p = __builtin_amdgcn_cvt_pk_fp8_f32(v.z / scale, v.w / scale, p, true);
  *(int*)(qx + base) = p;
  if ((threadIdx.x & 31) == 0) {
    const int blk = tid >> 5;   // linear 128-block id
    const int m = blk >> 5;     // blk / (K/128)
    const int kb = blk & 31;    // blk % (K/128)
    sx[kb * Mdim + m] = scale;
  }
}

// ---------------- weight quantize: (128 x 128) blocks ----------------
// One 256-thread block per weight block; 64 elems/thread kept in registers.
__global__ __launch_bounds__(256) void quant_w_kernel(const float* __restrict__ w,
                                                      uint8_t* __restrict__ qw,
                                                      float* __restrict__ sw) {
  const int kb = blockIdx.x, nb = blockIdx.y;
  const int t = threadIdx.x;
  const int r = t >> 1;              // row within block: 0..127
  const int c0 = (t & 1) * 64;       // col start: 0 or 64
  const int64_t gbase = (int64_t)(nb * 128 + r) * Kdim + kb * 128 + c0;
  float4 v[16];
  float a = 0.0f;
#pragma unroll
  for (int i = 0; i < 16; ++i) {
    v[i] = *(const float4*)(w + gbase + i * 4);
    a = fmaxf(a, fmaxf(fmaxf(fabsf(v[i].x), fabsf(v[i].y)),
                       fmaxf(fabsf(v[i].z), fabsf(v[i].w))));
  }
#pragma unroll
  for (int off = 32; off >= 1; off >>= 1) a = fmaxf(a, __shfl_xor(a, off, 64));
  __shared__ float red[4];
  if ((t & 63) == 0) red[t >> 6] = a;
  __syncthreads();
  a = fmaxf(fmaxf(red[0], red[1]), fmaxf(red[2], red[3]));
  const float scale = fmaxf(a, QEPS) / FP8MAX;
#pragma unroll
  for (int i = 0; i < 16; ++i) {
    int p = __builtin_amdgcn_cvt_pk_fp8_f32(v[i].x / scale, v[i].y / scale, 0, false);
    p = __builtin_amdgcn_cvt_pk_fp8_f32(v[i].z / scale, v[i].w / scale, p, true);
    *(int*)(qw + gbase + i * 4) = p;
  }
  if (t == 0) sw[nb * KBLK + kb] = scale;
}

// ---------------- blockwise-fp8 GEMM: out = (qx*sx) @ (qw*sw)^T + bias ----------------
// BM=BN=BK=128; 4 waves in 2x2; each wave 4x4 grid of 16x16x32 fp8 MFMAs.
__global__ __launch_bounds__(256) void gemm_kernel(
    const uint8_t* __restrict__ qx, const uint8_t* __restrict__ qw,
    const float* __restrict__ sx, const float* __restrict__ sw,
    const float* __restrict__ bias, float* __restrict__ out) {
  __shared__ __align__(16) uint8_t As[128 * 128];
  __shared__ __align__(16) uint8_t Bs[128 * 128];
  __shared__ __align__(16) float Ssx[128];

  const int tid = threadIdx.x;
  const int wid = tid >> 6;
  const int lane = tid & 63;
  const int bn = blockIdx.x, bm = blockIdx.y;
  const int wm = wid >> 1, wn = wid & 1;
  const int m0 = bm * 128, n0 = bn * 128;
  const int lr = lane & 15;   // A row / B col / C col
  const int lq = lane >> 4;   // lane quad

  const v4f zero4 = {0.f, 0.f, 0.f, 0.f};
  v4f acc[4][4];
#pragma unroll
  for (int i = 0; i < 4; ++i)
#pragma unroll
    for (int j = 0; j < 4; ++j) acc[i][j] = zero4;

  // staging: thread t loads 16B; LDS dest = wave-uniform base + lane*16
  const int srow = tid >> 3;
  const int scol = (tid & 7) << 4;
  const uint8_t* gA = qx + (int64_t)(m0 + srow) * Kdim + scol;
  const uint8_t* gB = qw + (int64_t)(n0 + srow) * Kdim + scol;
  uint8_t* ldsA = As + wid * 1024;
  uint8_t* ldsB = Bs + wid * 1024;
  const float* swrow = sw + bn * KBLK;

  for (int kb = 0; kb < KBLK; ++kb) {
    const int koff = kb * 128;
#pragma unroll
    for (int j = 0; j < 4; ++j) {
      async16(ldsA + j * 4096, gA + (int64_t)(j * 32) * Kdim + koff);
      async16(ldsB + j * 4096, gB + (int64_t)(j * 32) * Kdim + koff);
    }
    if (tid < 128) Ssx[tid] = sx[kb * Mdim + m0 + tid];
    __syncthreads();  // drains vmcnt -> async LDS writes visible

    v4f inner[4][4];
#pragma unroll
    for (int ks = 0; ks < 4; ++ks) {
      long long a[4], b[4];
#pragma unroll
      for (int i = 0; i < 4; ++i)
        a[i] = *(const long long*)(As + (wm * 64 + i * 16 + lr) * 128 + ks * 32 + lq * 8);
#pragma unroll
      for (int j = 0; j < 4; ++j)
        b[j] = *(const long long*)(Bs + (wn * 64 + j * 16 + lr) * 128 + ks * 32 + lq * 8);
#pragma unroll
      for (int i = 0; i < 4; ++i)
#pragma unroll
        for (int j = 0; j < 4; ++j)
          inner[i][j] = __builtin_amdgcn_mfma_f32_16x16x32_fp8_fp8(
              a[i], b[j], ks == 0 ? zero4 : inner[i][j], 0, 0, 0);
    }

    const float sww = swrow[kb];
#pragma unroll
    for (int i = 0; i < 4; ++i) {
      v4f s4 = *(const v4f*)&Ssx[wm * 64 + i * 16 + lq * 4];
      s4 *= sww;
#pragma unroll
      for (int j = 0; j < 4; ++j) acc[i][j] += s4 * inner[i][j];
    }
    __syncthreads();  // protect LDS before next stage
  }

  // epilogue: C layout col=lane&15, row=(lane>>4)*4+reg
#pragma unroll
  for (int i = 0; i < 4; ++i) {
    const int grow = m0 + wm * 64 + i * 16 + lq * 4;
#pragma unroll
    for (int j = 0; j < 4; ++j) {
      const int gcol = n0 + wn * 64 + j * 16 + lr;
      const float bv = bias[gcol];
      float* p = out + (int64_t)grow * Ndim + gcol;
      p[0] = acc[i][j][0] + bv;
      p[Ndim] = acc[i][j][1] + bv;
      p[2 * Ndim] = acc[i][j][2] + bv;
      p[3 * Ndim] = acc[i][j][3] + bv;
    }
  }
}

extern "C" void kernel_launch(void* const* d_in, const int* in_sizes, int n_in,
                              void* d_out, int out_size, void* d_ws, size_t ws_size,
                              hipStream_t stream) {
  const float* x = (const float*)d_in[0];
  const float* w = (const float*)d_in[1];
  const float* bias = (const float*)d_in[2];
  float* out = (float*)d_out;

  uint8_t* ws = (uint8_t*)d_ws;
  uint8_t* qx = ws;                                  // M*K fp8
  uint8_t* qw = qx + (size_t)Mdim * Kdim;            // N*K fp8
  float* sx = (float*)(qw + (size_t)Ndim * Kdim);    // [KBLK][M]
  float* sw = sx + (size_t)KBLK * Mdim;              // [NBLK][KBLK]

  quant_x_kernel<<<(Mdim / 256) * (Kdim / 4), 256, 0, stream>>>(x, qx, sx);
  quant_w_kernel<<<dim3(KBLK, NBLK), 256, 0, stream>>>(w, qw, sw);
  gemm_kernel<<<dim3(NBLK, Mdim / 128), 256, 0, stream>>>(qx, qw, sx, sw, bias, out);
}